// Round 2
// baseline (608.253 us; speedup 1.0000x reference)
//
#include <hip/hip_runtime.h>
#include <math.h>

#define T 32
#define K 2048
#define NBLOCKS 256
#define NTHREADS 256
#define LOG2PI_F 1.8378770664093453f
#define LOG_K_F  7.6246189861593985f    // log(2048)
#define SP_F     0.17677669529663687f   // sqrt(1/32)
#define LOG_SP_F (-1.7328679513998633f) // log(sqrt(1/32))

// ---------------------------------------------------------------------------
// barrier state init (ws is poisoned 0xAA before every timed launch)
// ---------------------------------------------------------------------------
__global__ void init_kernel(int* bar) {
    bar[0] = 0;  // arrival count
    bar[1] = 0;  // generation
}

// sense-reversing grid barrier, device (agent) scope.
// All NBLOCKS blocks are co-resident: 256 blocks x 4 waves = 1024 waves
// (capacity 8192), 17KB LDS, so no deadlock risk.
__device__ __forceinline__ void grid_barrier(int* count, int* gen) {
    __syncthreads();
    if (threadIdx.x == 0) {
        // read generation BEFORE arriving (avoids missed-wakeup race)
        int my = __hip_atomic_load(gen, __ATOMIC_RELAXED, __HIP_MEMORY_SCOPE_AGENT);
        // ACQ_REL: release this block's stores to device scope
        int arrived = __hip_atomic_fetch_add(count, 1, __ATOMIC_ACQ_REL, __HIP_MEMORY_SCOPE_AGENT);
        if (arrived == NBLOCKS - 1) {
            __hip_atomic_store(count, 0, __ATOMIC_RELAXED, __HIP_MEMORY_SCOPE_AGENT);
            __hip_atomic_fetch_add(gen, 1, __ATOMIC_RELEASE, __HIP_MEMORY_SCOPE_AGENT);
        } else {
            while (__hip_atomic_load(gen, __ATOMIC_RELAXED, __HIP_MEMORY_SCOPE_AGENT) == my) {
                __builtin_amdgcn_s_sleep(1);
            }
            // one acquire to invalidate local caches now that data is published
            (void)__hip_atomic_load(gen, __ATOMIC_ACQUIRE, __HIP_MEMORY_SCOPE_AGENT);
        }
    }
    __syncthreads();
}

// ---------------------------------------------------------------------------
// fully fused chain: setup -> 31 log-matmul-mean-exp steps -> final logsumexp
// grid must be exactly NBLOCKS x NTHREADS (65536 threads == T*K)
// ---------------------------------------------------------------------------
__global__ __launch_bounds__(NTHREADS) void fused_kernel(
    const float* __restrict__ means, const float* __restrict__ log_stds,
    const float* __restrict__ eps, float* __restrict__ zs,
    float* __restrict__ cterm, float* __restrict__ rb0, float* __restrict__ rb1,
    int* __restrict__ bar, float* __restrict__ out)
{
    __shared__ float2 sh[K];        // (z_j, r_j) for the current step
    __shared__ float red[NTHREADS]; // final-reduction scratch

    int* bcount = bar;
    int* bgen   = bar + 1;

    // ---- setup: one thread per (t,k) ----
    int gid = blockIdx.x * NTHREADS + threadIdx.x;  // 0 .. T*K-1
    {
        int t = gid >> 11;          // / K
        float mu = means[t];
        float ls = log_stds[t];
        float std_t = expf(ls);
        float z = fmaf(std_t, eps[gid], mu);
        zs[gid] = z;
        float zq = (z - mu) / std_t;
        float log_q = -0.5f * zq * zq - logf(std_t) - 0.5f * LOG2PI_F;
        cterm[gid] = -LOG_SP_F - 0.5f * LOG2PI_F - log_q;
        if (t == 0) {
            float zz = z / SP_F;
            float lp = -0.5f * zz * zz - LOG_SP_F - 0.5f * LOG2PI_F;
            rb0[gid] = lp - log_q;  // gid == k when t == 0
        }
    }
    grid_barrier(bcount, bgen);

    // ---- 31 chain steps ----
    int lane = threadIdx.x & 63;
    int wave = threadIdx.x >> 6;
    int gw = blockIdx.x * 4 + wave;  // global wave id, 0..1023; 2 columns each

    float* rin = rb0;
    float* rout = rb1;
    for (int i = 0; i < T - 1; ++i) {
        // stage (z_i[j], r[j]) into LDS
        const float* zrow = zs + i * K;
        #pragma unroll
        for (int j = threadIdx.x; j < K; j += NTHREADS)
            sh[j] = make_float2(zrow[j], rin[j]);
        __syncthreads();

        // pull this lane's 32-element j-chunk into registers (shared by both columns)
        float zv[32], rv[32];
        #pragma unroll
        for (int it = 0; it < 32; ++it) {
            float2 p = sh[lane + (it << 6)];
            zv[it] = p.x;
            rv[it] = p.y;
        }

        #pragma unroll
        for (int c = 0; c < 2; ++c) {
            int col = gw * 2 + c;
            float zp = zs[(i + 1) * K + col];
            float vals[32];
            float m = -INFINITY;
            #pragma unroll
            for (int it = 0; it < 32; ++it) {
                float d = zp - zv[it];
                float v = fmaf(-16.0f * d, d, rv[it]);  // r[j] - 16*d^2  (0.5/sp^2 == 16)
                vals[it] = v;
                m = fmaxf(m, v);
            }
            #pragma unroll
            for (int off = 32; off >= 1; off >>= 1)
                m = fmaxf(m, __shfl_xor(m, off, 64));
            float s = 0.0f;
            #pragma unroll
            for (int it = 0; it < 32; ++it)
                s += __expf(vals[it] - m);
            #pragma unroll
            for (int off = 32; off >= 1; off >>= 1)
                s += __shfl_xor(s, off, 64);
            if (lane == 0)
                rout[col] = cterm[(i + 1) * K + col] + m + logf(s) - LOG_K_F;
        }

        grid_barrier(bcount, bgen);  // publish rout before next step reads it
        float* tmp = rin; rin = rout; rout = tmp;
    }

    // ---- final: out = logmeanexp_j( r[j] + logN(0.5; z_{T-1,j}, 1) ), block 0 only ----
    if (blockIdx.x == 0) {
        int tid = threadIdx.x;
        const float* zlast = zs + (T - 1) * K;
        float vals[8];
        float m = -INFINITY;
        #pragma unroll
        for (int it = 0; it < 8; ++it) {
            int j = tid + it * NTHREADS;
            float d = 0.5f - zlast[j];
            float v = rin[j] + fmaf(-0.5f * d, d, -0.5f * LOG2PI_F);
            vals[it] = v;
            m = fmaxf(m, v);
        }
        red[tid] = m; __syncthreads();
        for (int off = 128; off >= 1; off >>= 1) {
            if (tid < off) red[tid] = fmaxf(red[tid], red[tid + off]);
            __syncthreads();
        }
        m = red[0]; __syncthreads();
        float s = 0.0f;
        #pragma unroll
        for (int it = 0; it < 8; ++it) s += __expf(vals[it] - m);
        red[tid] = s; __syncthreads();
        for (int off = 128; off >= 1; off >>= 1) {
            if (tid < off) red[tid] += red[tid + off];
            __syncthreads();
        }
        if (tid == 0) out[0] = m + logf(red[0]) - LOG_K_F;
    }
}

extern "C" void kernel_launch(void* const* d_in, const int* in_sizes, int n_in,
                              void* d_out, int out_size, void* d_ws, size_t ws_size,
                              hipStream_t stream) {
    const float* means    = (const float*)d_in[0];
    const float* log_stds = (const float*)d_in[1];
    const float* eps      = (const float*)d_in[2];
    float* out = (float*)d_out;

    float* ws    = (float*)d_ws;
    float* zs    = ws;               // T*K floats
    float* cterm = ws + T * K;       // T*K floats
    float* rb0   = ws + 2 * T * K;   // K floats
    float* rb1   = rb0 + K;          // K floats
    int*   bar   = (int*)(rb1 + K);  // 2 ints

    init_kernel<<<1, 1, 0, stream>>>(bar);
    fused_kernel<<<NBLOCKS, NTHREADS, 0, stream>>>(
        means, log_stds, eps, zs, cterm, rb0, rb1, bar, out);
}

// Round 3
// 217.384 us; speedup vs baseline: 2.7981x; 2.7981x over previous
//
#include <hip/hip_runtime.h>
#include <math.h>

#define T 32
#define K 2048
#define NBLOCKS 256
#define NTHREADS 256
#define LOG2PI_F 1.8378770664093453f
#define LOG_K_F  7.6246189861593985f    // log(2048)
#define SP_F     0.17677669529663687f   // sqrt(1/32)
#define LOG_SP_F (-1.7328679513998633f) // log(sqrt(1/32))
#define ZTAG 0x5A5A0001                 // tag for static z rows (never == 0xAAAAAAAA poison)

// 8-byte {value, tag} message, published/consumed as a single relaxed
// agent-scope atomic (sc0 sc1 -> bypasses non-coherent L1/L2, lands at MALL).
// No fences needed: the data IS the message (single-copy atomic 8B).
union Pack { float2 f; unsigned long long u; };

__device__ __forceinline__ float2 aload8(const float2* p) {
    Pack pk;
    pk.u = __hip_atomic_load((const unsigned long long*)p,
                             __ATOMIC_RELAXED, __HIP_MEMORY_SCOPE_AGENT);
    return pk.f;
}
__device__ __forceinline__ void astore8(float2* p, float v, int tag) {
    Pack pk; pk.f.x = v; pk.f.y = __int_as_float(tag);
    __hip_atomic_store((unsigned long long*)p, pk.u,
                       __ATOMIC_RELAXED, __HIP_MEMORY_SCOPE_AGENT);
}

// Fully fused dataflow chain. Grid MUST be NBLOCKS x NTHREADS.
// Block b owns columns [8b, 8b+8) for every timestep. Per step it polls the
// previous r-vector (tag == step+1) + the static z-row, computes its 8
// columns' logmeanexp, and publishes 8 tagged messages. Two ping-pong r
// buffers suffice: a slot for step s+2 can only be written after its writer
// consumed ALL of step s+1, which required every block to finish reading
// step s (full-consumption-before-production invariant).
__global__ __launch_bounds__(NTHREADS) void fused_kernel(
    const float* __restrict__ means, const float* __restrict__ log_stds,
    const float* __restrict__ eps, float2* __restrict__ zpack,
    float2* __restrict__ rbuf, float* __restrict__ out)
{
    __shared__ float sh_z[K];
    __shared__ float sh_r[K];
    __shared__ float lz[T][8];   // own columns' z  (z' for the compute phase)
    __shared__ float lc[T][8];   // own columns' cterm
    __shared__ float red[NTHREADS];

    const int tid  = threadIdx.x;
    const int b    = blockIdx.x;
    const int col0 = b * 8;

    // ---- setup: thread (t = tid>>3, dcol = tid&7) handles (t, col0+dcol) ----
    {
        int t = tid >> 3, dcol = tid & 7;
        float mu = means[t];
        float st = expf(log_stds[t]);
        float z  = fmaf(st, eps[t * K + col0 + dcol], mu);
        float zq = (z - mu) / st;
        float log_q = -0.5f * zq * zq - logf(st) - 0.5f * LOG2PI_F;
        lz[t][dcol] = z;
        lc[t][dcol] = -LOG_SP_F - 0.5f * LOG2PI_F - log_q;   // cterm[t, col]
        astore8(&zpack[t * K + col0 + dcol], z, ZTAG);
        if (t == 0) {
            float zz = z / SP_F;
            float r0 = -0.5f * zz * zz - LOG_SP_F - 0.5f * LOG2PI_F - log_q;
            astore8(&rbuf[col0 + dcol], r0, 1);              // r_0, tag 1
        }
    }
    __syncthreads();

    const int lane = tid & 63;
    const int wave = tid >> 6;

    for (int s = 0; s < T - 1; ++s) {
        // ---- stage z-row s and r_s into LDS (poll tagged messages) ----
        const float2* zrow = zpack + s * K;
        const float2* rrow = rbuf + (s & 1) * K;
        const int rtag = s + 1;
        float2 zv[8], rv[8];
        #pragma unroll
        for (int q = 0; q < 8; ++q) {            // 16 independent loads in flight
            zv[q] = aload8(&zrow[tid + q * 256]);
            rv[q] = aload8(&rrow[tid + q * 256]);
        }
        #pragma unroll
        for (int q = 0; q < 8; ++q) {            // re-poll stragglers only
            while (__float_as_int(zv[q].y) != ZTAG) {
                __builtin_amdgcn_s_sleep(1);
                zv[q] = aload8(&zrow[tid + q * 256]);
            }
            while (__float_as_int(rv[q].y) != rtag) {
                __builtin_amdgcn_s_sleep(1);
                rv[q] = aload8(&rrow[tid + q * 256]);
            }
        }
        #pragma unroll
        for (int q = 0; q < 8; ++q) {
            sh_z[tid + q * 256] = zv[q].x;
            sh_r[tid + q * 256] = rv[q].x;
        }
        __syncthreads();

        // ---- pull this lane's 32-element j-chunk into registers ----
        float zreg[32], rreg[32];
        #pragma unroll
        for (int it = 0; it < 32; ++it) {
            int j = lane + (it << 6);
            zreg[it] = sh_z[j];
            rreg[it] = sh_r[j];
        }

        // ---- each wave computes its 2 columns ----
        #pragma unroll
        for (int cidx = 0; cidx < 2; ++cidx) {
            int dc = wave * 2 + cidx;
            float zp = lz[s + 1][dc];
            float ct = lc[s + 1][dc];
            float vals[32];
            float m = -INFINITY;
            #pragma unroll
            for (int it = 0; it < 32; ++it) {
                float d = zp - zreg[it];
                float v = fmaf(-16.0f * d, d, rreg[it]);   // r_j - 16 d^2 (0.5/sp^2 == 16)
                vals[it] = v;
                m = fmaxf(m, v);
            }
            #pragma unroll
            for (int off = 32; off >= 1; off >>= 1)
                m = fmaxf(m, __shfl_xor(m, off, 64));
            float ssum = 0.0f;
            #pragma unroll
            for (int it = 0; it < 32; ++it)
                ssum += __expf(vals[it] - m);
            #pragma unroll
            for (int off = 32; off >= 1; off >>= 1)
                ssum += __shfl_xor(ssum, off, 64);
            if (lane == 0)
                astore8(&rbuf[((s + 1) & 1) * K + col0 + dc],
                        ct + m + logf(ssum) - LOG_K_F, s + 2);
        }
        __syncthreads();   // protect sh_z/sh_r before next step's staging
    }

    // ---- final logmeanexp over r_31 + likelihood, block 0 only ----
    if (b == 0) {
        const float2* zrow = zpack + (T - 1) * K;
        const float2* rrow = rbuf + ((T - 1) & 1) * K;   // rbuf[1], tag 32
        float vals[8];
        float m = -INFINITY;
        #pragma unroll
        for (int q = 0; q < 8; ++q) {
            int j = tid + q * 256;
            float2 zmsg = aload8(&zrow[j]);
            while (__float_as_int(zmsg.y) != ZTAG) {
                __builtin_amdgcn_s_sleep(1);
                zmsg = aload8(&zrow[j]);
            }
            float2 rmsg = aload8(&rrow[j]);
            while (__float_as_int(rmsg.y) != T) {
                __builtin_amdgcn_s_sleep(1);
                rmsg = aload8(&rrow[j]);
            }
            float d = 0.5f - zmsg.x;
            float v = rmsg.x + fmaf(-0.5f * d, d, -0.5f * LOG2PI_F);
            vals[q] = v;
            m = fmaxf(m, v);
        }
        red[tid] = m; __syncthreads();
        for (int off = 128; off >= 1; off >>= 1) {
            if (tid < off) red[tid] = fmaxf(red[tid], red[tid + off]);
            __syncthreads();
        }
        m = red[0]; __syncthreads();
        float ssum = 0.0f;
        #pragma unroll
        for (int q = 0; q < 8; ++q) ssum += __expf(vals[q] - m);
        red[tid] = ssum; __syncthreads();
        for (int off = 128; off >= 1; off >>= 1) {
            if (tid < off) red[tid] += red[tid + off];
            __syncthreads();
        }
        if (tid == 0) out[0] = m + logf(red[0]) - LOG_K_F;
    }
}

extern "C" void kernel_launch(void* const* d_in, const int* in_sizes, int n_in,
                              void* d_out, int out_size, void* d_ws, size_t ws_size,
                              hipStream_t stream) {
    const float* means    = (const float*)d_in[0];
    const float* log_stds = (const float*)d_in[1];
    const float* eps      = (const float*)d_in[2];
    float* out = (float*)d_out;

    float2* zpack = (float2*)d_ws;          // T*K messages {z, ZTAG}
    float2* rbuf  = zpack + T * K;          // 2*K ping-pong messages {r, step-tag}

    fused_kernel<<<NBLOCKS, NTHREADS, 0, stream>>>(
        means, log_stds, eps, zpack, rbuf, out);
}

// Round 4
// 193.327 us; speedup vs baseline: 3.1462x; 1.1244x over previous
//
#include <hip/hip_runtime.h>
#include <math.h>

#define T 32
#define K 2048
#define NBLOCKS 256
#define NTHREADS 256
#define LOG2PI_F 1.8378770664093453f
#define LOG_K_F  7.6246189861593985f    // log(2048)
#define SP_F     0.17677669529663687f   // sqrt(1/32)
#define LOG_SP_F (-1.7328679513998633f) // log(sqrt(1/32))

// 8-byte {value, tag} message as a single relaxed agent-scope atomic
// (bypasses non-coherent L1/L2, lands at the coherence point; the data IS
// the flag, so no release/acquire cache maintenance is ever needed).
union Pack { float2 f; unsigned long long u; };

__device__ __forceinline__ float2 aload8(const float2* p) {
    Pack pk;
    pk.u = __hip_atomic_load((const unsigned long long*)p,
                             __ATOMIC_RELAXED, __HIP_MEMORY_SCOPE_AGENT);
    return pk.f;
}
__device__ __forceinline__ void astore8(float2* p, float v, int tag) {
    Pack pk; pk.f.x = v; pk.f.y = __int_as_float(tag);
    __hip_atomic_store((unsigned long long*)p, pk.u,
                       __ATOMIC_RELAXED, __HIP_MEMORY_SCOPE_AGENT);
}

// Fully fused dataflow chain, r-messages only. Block b owns columns
// [8b, 8b+8). z-rows are recomputed locally from eps (inputs are pristine
// and cached — no cross-block traffic). Two ping-pong r buffers suffice:
// publishing step s+2 requires having consumed ALL of step s+1, which
// required every block to have published s+1, hence consumed s — no reader
// of step s can be lapped. Tags 1..32 never collide with 0xAAAAAAAA poison.
__global__ __launch_bounds__(NTHREADS) void fused_kernel(
    const float* __restrict__ means, const float* __restrict__ log_stds,
    const float* __restrict__ eps, float2* __restrict__ rbuf,
    float* __restrict__ out)
{
    __shared__ float2 shzr[K];      // (z_j, R_j = r_j - 16 z_j^2)
    __shared__ float smu[T], sstd[T];
    __shared__ float lz[T][8];      // own columns' z'
    __shared__ float lc[T][8];      // own columns' cterm
    __shared__ float red[NTHREADS];

    const int tid  = threadIdx.x;
    const int b    = blockIdx.x;
    const int col0 = b * 8;

    // ---- setup: thread (t = tid>>3, dcol = tid&7) handles (t, col0+dcol) ----
    {
        int t = tid >> 3, dcol = tid & 7;
        float mu = means[t];
        float st = expf(log_stds[t]);
        if (dcol == 0) { smu[t] = mu; sstd[t] = st; }
        float e = eps[t * K + col0 + dcol];
        float z = fmaf(st, e, mu);
        // (z - mu)/st == e exactly, so log_q = -0.5 e^2 - log(st) - 0.5 log2pi
        float log_q = fmaf(-0.5f * e, e, -logf(st) - 0.5f * LOG2PI_F);
        lz[t][dcol] = z;
        lc[t][dcol] = -LOG_SP_F - 0.5f * LOG2PI_F - log_q;
        if (t == 0) {
            float zz = z / SP_F;
            float r0 = -0.5f * zz * zz - LOG_SP_F - 0.5f * LOG2PI_F - log_q;
            astore8(&rbuf[col0 + dcol], r0, 1);   // r_0 into slot 0, tag 1
        }
    }
    __syncthreads();

    const int lane = tid & 63;
    const int wave = tid >> 6;

    for (int s = 0; s < T - 1; ++s) {
        const float mu_s  = smu[s];
        const float std_s = sstd[s];

        // independent cached eps loads first — they complete under the poll
        const float* erow = eps + s * K;
        float ev[8];
        #pragma unroll
        for (int q = 0; q < 8; ++q) ev[q] = erow[tid + q * 256];

        // ---- batched poll of the r-row (all 8 loads in flight per sweep) ----
        const float2* rrow = rbuf + (s & 1) * K;
        const int rtag = s + 1;
        float2 rv[8];
        #pragma unroll
        for (int q = 0; q < 8; ++q) rv[q] = aload8(&rrow[tid + q * 256]);
        for (;;) {
            bool ready = true;
            #pragma unroll
            for (int q = 0; q < 8; ++q)
                ready &= (__float_as_int(rv[q].y) == rtag);
            if (ready) break;
            __builtin_amdgcn_s_sleep(1);
            #pragma unroll
            for (int q = 0; q < 8; ++q) rv[q] = aload8(&rrow[tid + q * 256]);
        }

        // ---- stage (z_j, R_j) into LDS ----
        #pragma unroll
        for (int q = 0; q < 8; ++q) {
            float z = fmaf(std_s, ev[q], mu_s);
            float R = fmaf(-16.0f * z, z, rv[q].x);
            shzr[tid + q * 256] = make_float2(z, R);
        }
        __syncthreads();

        // ---- pull this lane's 32-element j-chunk into registers ----
        float2 fr[32];
        #pragma unroll
        for (int it = 0; it < 32; ++it) fr[it] = shzr[lane + (it << 6)];

        // ---- each wave computes its 2 columns ----
        #pragma unroll
        for (int c = 0; c < 2; ++c) {
            int dc = wave * 2 + c;
            float zp = lz[s + 1][dc];
            float tz = 32.0f * zp;
            float vals[32];
            float m = -INFINITY;
            #pragma unroll
            for (int it = 0; it < 32; ++it) {
                // r_j - 16 (z'-z_j)^2 = (R_j + 32 z' z_j) - 16 z'^2; const folds out
                float v = fmaf(tz, fr[it].x, fr[it].y);
                vals[it] = v;
                m = fmaxf(m, v);
            }
            #pragma unroll
            for (int off = 32; off >= 1; off >>= 1)
                m = fmaxf(m, __shfl_xor(m, off, 64));
            float ssum = 0.0f;
            #pragma unroll
            for (int it = 0; it < 32; ++it)
                ssum += __expf(vals[it] - m);
            #pragma unroll
            for (int off = 32; off >= 1; off >>= 1)
                ssum += __shfl_xor(ssum, off, 64);
            if (lane == 0) {
                float ct = lc[s + 1][dc];
                float r_new = fmaf(-16.0f * zp, zp, ct) + m + logf(ssum) - LOG_K_F;
                astore8(&rbuf[((s + 1) & 1) * K + col0 + dc], r_new, s + 2);
            }
        }
        __syncthreads();   // protect shzr before next step's staging
    }

    // ---- final logmeanexp over r_31 + likelihood, block 0 only ----
    if (b == 0) {
        const float* erow = eps + (T - 1) * K;
        const float mu_l  = smu[T - 1];
        const float std_l = sstd[T - 1];
        const float2* rrow = rbuf + ((T - 1) & 1) * K;   // slot 1, tag 32
        float ev[8];
        #pragma unroll
        for (int q = 0; q < 8; ++q) ev[q] = erow[tid + q * 256];
        float2 rv[8];
        #pragma unroll
        for (int q = 0; q < 8; ++q) rv[q] = aload8(&rrow[tid + q * 256]);
        for (;;) {
            bool ready = true;
            #pragma unroll
            for (int q = 0; q < 8; ++q)
                ready &= (__float_as_int(rv[q].y) == T);
            if (ready) break;
            __builtin_amdgcn_s_sleep(1);
            #pragma unroll
            for (int q = 0; q < 8; ++q) rv[q] = aload8(&rrow[tid + q * 256]);
        }
        float vals[8];
        float m = -INFINITY;
        #pragma unroll
        for (int q = 0; q < 8; ++q) {
            float z = fmaf(std_l, ev[q], mu_l);
            float d = 0.5f - z;
            float v = rv[q].x + fmaf(-0.5f * d, d, -0.5f * LOG2PI_F);
            vals[q] = v;
            m = fmaxf(m, v);
        }
        red[tid] = m; __syncthreads();
        for (int off = 128; off >= 1; off >>= 1) {
            if (tid < off) red[tid] = fmaxf(red[tid], red[tid + off]);
            __syncthreads();
        }
        m = red[0]; __syncthreads();
        float ssum = 0.0f;
        #pragma unroll
        for (int q = 0; q < 8; ++q) ssum += __expf(vals[q] - m);
        red[tid] = ssum; __syncthreads();
        for (int off = 128; off >= 1; off >>= 1) {
            if (tid < off) red[tid] += red[tid + off];
            __syncthreads();
        }
        if (tid == 0) out[0] = m + logf(red[0]) - LOG_K_F;
    }
}

extern "C" void kernel_launch(void* const* d_in, const int* in_sizes, int n_in,
                              void* d_out, int out_size, void* d_ws, size_t ws_size,
                              hipStream_t stream) {
    const float* means    = (const float*)d_in[0];
    const float* log_stds = (const float*)d_in[1];
    const float* eps      = (const float*)d_in[2];
    float* out = (float*)d_out;

    float2* rbuf = (float2*)d_ws;   // 2*K ping-pong messages {r, step-tag}

    fused_kernel<<<NBLOCKS, NTHREADS, 0, stream>>>(
        means, log_stds, eps, rbuf, out);
}

// Round 5
// 176.954 us; speedup vs baseline: 3.4374x; 1.0925x over previous
//
#include <hip/hip_runtime.h>
#include <math.h>

#define T 32
#define K 2048
#define NBLOCKS 256
#define NTHREADS 512
#define QS 4                            // K / NTHREADS message slots per thread
#define LOG2PI_F 1.8378770664093453f
#define LOG_K_F  7.6246189861593985f    // log(2048)
#define SP_F     0.17677669529663687f   // sqrt(1/32)
#define LOG_SP_F (-1.7328679513998633f) // log(sqrt(1/32))

// 8-byte {value, tag} message as a single relaxed agent-scope atomic
// (bypasses non-coherent L1/L2, lands at the coherence point; the data IS
// the flag, so no release/acquire cache maintenance is ever needed).
union Pack { float2 f; unsigned long long u; };

__device__ __forceinline__ float2 aload8(const float2* p) {
    Pack pk;
    pk.u = __hip_atomic_load((const unsigned long long*)p,
                             __ATOMIC_RELAXED, __HIP_MEMORY_SCOPE_AGENT);
    return pk.f;
}
__device__ __forceinline__ void astore8(float2* p, float v, int tag) {
    Pack pk; pk.f.x = v; pk.f.y = __int_as_float(tag);
    __hip_atomic_store((unsigned long long*)p, pk.u,
                       __ATOMIC_RELAXED, __HIP_MEMORY_SCOPE_AGENT);
}

// Fully fused dataflow chain, r-messages only. Block b owns columns
// [8b, 8b+8), one column per wave (8 waves). z-rows are recomputed locally
// from eps. Two ping-pong r buffers suffice (full-consumption-before-
// production invariant, see R3). Tags 1..32 never collide with 0xAA poison.
// LDS (z,R) staging is parity-double-buffered -> ONE __syncthreads per step.
__global__ __launch_bounds__(NTHREADS) void fused_kernel(
    const float* __restrict__ means, const float* __restrict__ log_stds,
    const float* __restrict__ eps, float2* __restrict__ rbuf,
    float* __restrict__ out)
{
    __shared__ float2 shzr[2][K];   // 32 KB: (z_j, R_j = r_j - 16 z_j^2)
    __shared__ float smu[T], sstd[T];
    __shared__ float lz[T][8];      // own columns' z'
    __shared__ float lc[T][8];      // own columns' cterm
    __shared__ float red[NTHREADS];

    const int tid  = threadIdx.x;
    const int b    = blockIdx.x;
    const int col0 = b * 8;

    // ---- setup: threads 0..255, thread (t = tid>>3, dcol = tid&7) ----
    if (tid < T * 8) {
        int t = tid >> 3, dcol = tid & 7;
        float mu = means[t];
        float st = expf(log_stds[t]);
        if (dcol == 0) { smu[t] = mu; sstd[t] = st; }
        float e = eps[t * K + col0 + dcol];
        float z = fmaf(st, e, mu);
        // (z - mu)/st == e exactly: log_q = -0.5 e^2 - log(st) - 0.5 log2pi
        float log_q = fmaf(-0.5f * e, e, -logf(st) - 0.5f * LOG2PI_F);
        lz[t][dcol] = z;
        lc[t][dcol] = -LOG_SP_F - 0.5f * LOG2PI_F - log_q;
        if (t == 0) {
            float zz = z / SP_F;
            float r0 = -0.5f * zz * zz - LOG_SP_F - 0.5f * LOG2PI_F - log_q;
            astore8(&rbuf[col0 + dcol], r0, 1);   // r_0 into slot 0, tag 1
        }
    }
    __syncthreads();

    const int lane = tid & 63;
    const int wave = tid >> 6;          // 0..7: one column per wave

    for (int s = 0; s < T - 1; ++s) {
        const int par = s & 1;
        const float mu_s  = smu[s];
        const float std_s = sstd[s];
        const float* erow = eps + s * K;

        // ---- stage z (r-independent) BEFORE the poll; keep z in registers ----
        float zloc[QS];
        #pragma unroll
        for (int q = 0; q < QS; ++q) {
            float e = erow[tid + q * NTHREADS];
            float z = fmaf(std_s, e, mu_s);
            zloc[q] = z;
            shzr[par][tid + q * NTHREADS].x = z;
        }

        // ---- poll r-row: first sweep loads all, retries reload ONLY misses ----
        const float2* rrow = rbuf + par * K;
        const int rtag = s + 1;
        float2 rv[QS];
        #pragma unroll
        for (int q = 0; q < QS; ++q) rv[q] = aload8(&rrow[tid + q * NTHREADS]);
        for (;;) {
            bool all = true;
            #pragma unroll
            for (int q = 0; q < QS; ++q)
                all &= (__float_as_int(rv[q].y) == rtag);
            if (all) break;
            __builtin_amdgcn_s_sleep(1);
            #pragma unroll
            for (int q = 0; q < QS; ++q)
                if (__float_as_int(rv[q].y) != rtag)      // exec-masked reload
                    rv[q] = aload8(&rrow[tid + q * NTHREADS]);
        }

        // ---- stage R = r - 16 z^2 (z still in registers) ----
        #pragma unroll
        for (int q = 0; q < QS; ++q)
            shzr[par][tid + q * NTHREADS].y =
                fmaf(-16.0f * zloc[q], zloc[q], rv[q].x);
        __syncthreads();   // the ONLY barrier this step (parity dbuf)

        // ---- pull this lane's 32-element j-chunk ----
        float2 fr[32];
        #pragma unroll
        for (int it = 0; it < 32; ++it) fr[it] = shzr[par][lane + (it << 6)];

        // ---- this wave's column ----
        float zp = lz[s + 1][wave];
        float tz = 32.0f * zp;
        float vals[32];
        float m = -INFINITY;
        #pragma unroll
        for (int it = 0; it < 32; ++it) {
            // r_j - 16 (z'-z_j)^2 = (R_j + 32 z' z_j) - 16 z'^2 (const folds out)
            float v = fmaf(tz, fr[it].x, fr[it].y);
            vals[it] = v;
            m = fmaxf(m, v);
        }
        #pragma unroll
        for (int off = 32; off >= 1; off >>= 1)
            m = fmaxf(m, __shfl_xor(m, off, 64));
        float ssum = 0.0f;
        #pragma unroll
        for (int it = 0; it < 32; ++it)
            ssum += __expf(vals[it] - m);
        #pragma unroll
        for (int off = 32; off >= 1; off >>= 1)
            ssum += __shfl_xor(ssum, off, 64);
        if (lane == 0) {
            float ct = lc[s + 1][wave];
            float rn = fmaf(-16.0f * zp, zp, ct) + m + logf(ssum) - LOG_K_F;
            astore8(&rbuf[(par ^ 1) * K + col0 + wave], rn, s + 2);
        }
        // no trailing barrier: next step writes the other parity, and step
        // s+2's same-parity writes are fenced by step s+1's __syncthreads
    }

    // ---- final logmeanexp over r_31 + likelihood, block 0 only ----
    if (b == 0) {
        const float* erow = eps + (T - 1) * K;
        const float mu_l  = smu[T - 1];
        const float std_l = sstd[T - 1];
        const float2* rrow = rbuf + ((T - 1) & 1) * K;   // parity 1, tag 32
        float ev[QS];
        #pragma unroll
        for (int q = 0; q < QS; ++q) ev[q] = erow[tid + q * NTHREADS];
        float2 rv[QS];
        #pragma unroll
        for (int q = 0; q < QS; ++q) rv[q] = aload8(&rrow[tid + q * NTHREADS]);
        for (;;) {
            bool all = true;
            #pragma unroll
            for (int q = 0; q < QS; ++q)
                all &= (__float_as_int(rv[q].y) == T);
            if (all) break;
            __builtin_amdgcn_s_sleep(1);
            #pragma unroll
            for (int q = 0; q < QS; ++q)
                if (__float_as_int(rv[q].y) != T)
                    rv[q] = aload8(&rrow[tid + q * NTHREADS]);
        }
        float vals[QS];
        float m = -INFINITY;
        #pragma unroll
        for (int q = 0; q < QS; ++q) {
            float z = fmaf(std_l, ev[q], mu_l);
            float d = 0.5f - z;
            float v = rv[q].x + fmaf(-0.5f * d, d, -0.5f * LOG2PI_F);
            vals[q] = v;
            m = fmaxf(m, v);
        }
        red[tid] = m; __syncthreads();
        for (int off = NTHREADS / 2; off >= 1; off >>= 1) {
            if (tid < off) red[tid] = fmaxf(red[tid], red[tid + off]);
            __syncthreads();
        }
        m = red[0]; __syncthreads();
        float ssum = 0.0f;
        #pragma unroll
        for (int q = 0; q < QS; ++q) ssum += __expf(vals[q] - m);
        red[tid] = ssum; __syncthreads();
        for (int off = NTHREADS / 2; off >= 1; off >>= 1) {
            if (tid < off) red[tid] += red[tid + off];
            __syncthreads();
        }
        if (tid == 0) out[0] = m + logf(red[0]) - LOG_K_F;
    }
}

extern "C" void kernel_launch(void* const* d_in, const int* in_sizes, int n_in,
                              void* d_out, int out_size, void* d_ws, size_t ws_size,
                              hipStream_t stream) {
    const float* means    = (const float*)d_in[0];
    const float* log_stds = (const float*)d_in[1];
    const float* eps      = (const float*)d_in[2];
    float* out = (float*)d_out;

    float2* rbuf = (float2*)d_ws;   // 2*K ping-pong messages {r, step-tag}

    fused_kernel<<<NBLOCKS, NTHREADS, 0, stream>>>(
        means, log_stds, eps, rbuf, out);
}